// Round 3
// baseline (430.599 us; speedup 1.0000x reference)
//
#include <hip/hip_runtime.h>
#include <hip/hip_cooperative_groups.h>

namespace cg = cooperative_groups;

// SemanticCaps dynamic routing, fp32. B=128, J=10, K=1152, M=16, I=8.
// R7 (resubmit — R2 bench was a GPU-acquisition timeout, no data):
// single persistent cooperative kernel. 256 blocks (1/CU) x 640 thr
// (wave = output capsule j, lane = batch b). Ws tile staged to LDS ONCE and
// reused across all 3 routing passes; xpose / iter / squash are phases
// separated by grid.sync() instead of 7 kernel launches. KT=9 (sp 10.5 MB).
// b-logit algebra: b after t iters = u.(v0+..+v_{t-1}) (b starts at 0).
//
// ws (floats): xT[9216*128] sp[128*10*128*16] v0T[20480] vsumT[20480]

#define B_ 128
#define J_ 10
#define K_ 1152
#define M_ 16
#define I_ 8
#define KT 9
#define NKT (K_ / KT)             // 128 k-tiles
#define RW (K_ * I_)              // 9216 rows of xT
#define WSL (KT * M_ * I_)        // 1152 floats per wave's Ws slice
#define EARR_OFF (J_ * WSL)       // 11520
#define SMEM_FLOATS (EARR_OFF + 2 * J_ * 64)   // 12800 floats = 51.2 KB

// ---------- one routing pass (phase) ----------------------------------------
// MODE 0: c == 1 (iteration 0; 0.1 folded into squash<0>)
// MODE 1: c = softmax_j(u . vin); s = sum_k c*u (u stays in registers)
template <int MODE>
__device__ __forceinline__ void route_pass(
    const float* __restrict__ xT, const float* __restrict__ wsl,
    float* __restrict__ earr, const float* __restrict__ vinT,
    float* __restrict__ sp, int kt, int j, int bl, int b)
{
    float s[M_];
#pragma unroll
    for (int m = 0; m < M_; ++m) s[m] = 0.f;
    float v[M_];
    if (MODE == 1) {
        const float4* vp = (const float4*)(vinT + ((size_t)j * B_ + b) * M_);
#pragma unroll
        for (int q = 0; q < 4; ++q) {
            const float4 w = vp[q];
            v[4*q] = w.x; v[4*q+1] = w.y; v[4*q+2] = w.z; v[4*q+3] = w.w;
        }
    }
    float xr[I_];
#pragma unroll
    for (int i = 0; i < I_; ++i) xr[i] = xT[(size_t)((kt * KT) * I_ + i) * B_ + b];

#pragma unroll
    for (int kk = 0; kk < KT; ++kk) {
        const float4* wv4 = (const float4*)wsl + kk * (M_ * I_ / 4);
        float u[M_];
#pragma unroll
        for (int m = 0; m < M_; ++m) {
            const float4 a4 = wv4[2*m];
            const float4 b4 = wv4[2*m+1];
            u[m] = a4.x*xr[0] + a4.y*xr[1] + a4.z*xr[2] + a4.w*xr[3]
                 + b4.x*xr[4] + b4.y*xr[5] + b4.z*xr[6] + b4.w*xr[7];
        }
        float xn[I_];
        if (kk + 1 < KT) {
#pragma unroll
            for (int i = 0; i < I_; ++i)
                xn[i] = xT[(size_t)((kt*KT + kk + 1) * I_ + i) * B_ + b];
        }
        if (MODE == 1) {
            float lg = 0.f;
#pragma unroll
            for (int m = 0; m < M_; ++m) lg += u[m] * v[m];
            const float e = __expf(lg);
            earr[(kk & 1) * (J_*64) + j * 64 + bl] = e;
            __syncthreads();   // one barrier/k; ping-pong makes reuse race-free
            float den = 0.f;
#pragma unroll
            for (int jj = 0; jj < J_; ++jj)
                den += earr[(kk & 1) * (J_*64) + jj * 64 + bl];
            const float c = __fdividef(e, den);
#pragma unroll
            for (int m = 0; m < M_; ++m) s[m] += c * u[m];
        } else {
#pragma unroll
            for (int m = 0; m < M_; ++m) s[m] += u[m];
        }
        if (kk + 1 < KT) {
#pragma unroll
            for (int i = 0; i < I_; ++i) xr[i] = xn[i];
        }
    }
    float4* o = (float4*)(sp + (((size_t)kt * J_ + j) * B_ + b) * M_);
#pragma unroll
    for (int q = 0; q < 4; ++q) {
        float4 w;
        w.x = s[4*q]; w.y = s[4*q+1]; w.z = s[4*q+2]; w.w = s[4*q+3];
        o[q] = w;
    }
}

// ---------- squash phase: 5 (j,b)-pairs per block, quarter-split over NKT ----
// SM 0: v0T = squash(0.1*S)  SM 1: vsumT = v0T + squash(S)  SM 2: out = squash(S)
template <int SM>
__device__ __forceinline__ void squash_phase(
    const float* __restrict__ sp, const float* __restrict__ v0T,
    float* __restrict__ dst, int bid, int t)
{
    const int w = t >> 6;
    if (w >= 5) return;                  // waves 5..9 idle this phase
    const int l  = t & 63;
    const int m  = l & 15;
    const int qt = l >> 4;               // quarter of the k-tiles
    const int p  = bid * 5 + w;          // (j,b) pair, 0..1279
    const int jj = p >> 7;
    const int bb = p & 127;
    const float* base = sp + ((size_t)(jj * B_ + bb) * M_ + m);
    float S = 0.f;
#pragma unroll 8
    for (int tt = qt * (NKT/4); tt < (qt + 1) * (NKT/4); ++tt)
        S += base[(size_t)tt * (J_ * B_ * M_)];
    S += __shfl_xor(S, 16, 64);
    S += __shfl_xor(S, 32, 64);          // fold 4 quarters -> full k-sum
    if (SM == 0) S *= 0.1f;
    float sq = S * S;
    sq += __shfl_xor(sq, 1, 64);
    sq += __shfl_xor(sq, 2, 64);
    sq += __shfl_xor(sq, 4, 64);
    sq += __shfl_xor(sq, 8, 64);         // sum over m within 16-lane group
    const float n = sqrtf(sq);
    float vv = S * (n / (1.f + sq));
    const int g = p * 16 + m;
    if (SM == 1) vv += v0T[g];
    if (qt == 0) {
        if (SM == 2) dst[((size_t)bb * J_ + jj) * M_ + m] = vv;  // [b][j][m]
        else         dst[g] = vv;                                 // vT layout
    }
}

// ---------- the single persistent kernel ------------------------------------
__global__ __launch_bounds__(640)
void fused_kernel(const float* __restrict__ x, const float* __restrict__ Ws,
                  float* __restrict__ xT, float* __restrict__ sp,
                  float* __restrict__ v0T, float* __restrict__ vsumT,
                  float* __restrict__ out)
{
    cg::grid_group grid = cg::this_grid();
    __shared__ float smem[SMEM_FLOATS];      // Ws slices + earr; head aliased by xpose tile
    const int t   = threadIdx.x;
    const int bid = blockIdx.x;

    // ---- phase X: transpose x[b][k][i] -> xT[k*8+i][b] (288 tiles / 256 blocks)
    {
        float* tile = smem;                  // 64*65 floats, aliases Ws region (pre-staging)
        const int lo = t & 63;
        const int hi = t >> 6;               // 0..9
        for (int tix = bid; tix < 288; tix += 256) {
            const int r0 = (tix >> 1) * 64;
            const int b0 = (tix & 1) * 64;
#pragma unroll
            for (int c = 0; c < 7; ++c) {
                const int bb = c * 10 + hi;
                if (bb < 64) tile[lo * 65 + bb] = x[(size_t)(b0 + bb) * RW + r0 + lo];
            }
            __syncthreads();
#pragma unroll
            for (int c = 0; c < 7; ++c) {
                const int r = c * 10 + hi;
                if (r < 64) xT[(size_t)(r0 + r) * B_ + b0 + lo] = tile[r * 65 + lo];
            }
            __syncthreads();
        }
    }
    grid.sync();

    const int bl = t & 63;
    const int j  = t >> 6;
    const int kt = bid >> 1, bg = bid & 1;
    const int b  = bg * 64 + bl;
    float* earr = smem + EARR_OFF;
    const float* wsl = smem + j * WSL;

    // ---- stage this wave's Ws slice ONCE (persists across all 3 passes) ----
    {
        const float4* src = (const float4*)(Ws + ((size_t)j * K_ + (size_t)kt * KT) * (M_ * I_));
        float4* dst = (float4*)smem + j * (WSL / 4);
        for (int q = bl; q < WSL / 4; q += 64) dst[q] = src[q];
        // no barrier needed: each wave reads only its own slice
    }

    route_pass<0>(xT, wsl, earr, nullptr, sp, kt, j, bl, b);
    grid.sync();
    squash_phase<0>(sp, nullptr, v0T, bid, t);
    grid.sync();
    route_pass<1>(xT, wsl, earr, v0T, sp, kt, j, bl, b);
    grid.sync();
    squash_phase<1>(sp, v0T, vsumT, bid, t);
    grid.sync();
    route_pass<1>(xT, wsl, earr, vsumT, sp, kt, j, bl, b);
    grid.sync();
    squash_phase<2>(sp, nullptr, out, bid, t);
}

extern "C" void kernel_launch(void* const* d_in, const int* in_sizes, int n_in,
                              void* d_out, int out_size, void* d_ws, size_t ws_size,
                              hipStream_t stream) {
    const float* x  = (const float*)d_in[0];   // [128][1152][8]
    const float* Ws = (const float*)d_in[1];   // [10][1152][16][8]
    float* out = (float*)d_out;                // [128][10][16]

    float* xT    = (float*)d_ws;                           // 1,179,648
    float* sp    = xT + (size_t)RW * B_;                   // 2,621,440
    float* v0T   = sp + (size_t)NKT * J_ * B_ * M_;        //    20,480
    float* vsumT = v0T + J_ * B_ * M_;                     //    20,480

    void* args[] = { (void*)&x, (void*)&Ws, (void*)&xT, (void*)&sp,
                     (void*)&v0T, (void*)&vsumT, (void*)&out };
    hipLaunchCooperativeKernel((const void*)fused_kernel, dim3(NKT * 2), dim3(640),
                               args, 0, stream);
}